// Round 5
// baseline (812.938 us; speedup 1.0000x reference)
//
#include <hip/hip_runtime.h>
#include <hip/hip_cooperative_groups.h>
#include <math.h>

namespace cg = cooperative_groups;

#define N_NODES 2048
#define N_EDGES 65536
#define SEQL 5
#define IN_F 32
#define HID 64
#define OUT_F 16
#define LN_EPS 1e-5f
#define NBLK 256
#define NTHR 512

struct Params {
    const float *x, *ew;
    const float *Wcz, *bcz, *Wlz, *blz;
    const float *Wch, *bch, *Wlh, *blh;
    const float *Wred, *bred, *Wc1, *bc1, *Wc2, *bc2;
    const float *g1, *be1, *g2, *be2, *Wout, *bout;
    const float *Wi1, *bi1, *Wi2, *bi2;
    const int *ei;
    float *deg; int *cnt; int *fill; int *rowptr;
    float *dinv, *dself; int *csrc; float *cnrm;
    float *Wzp, *Whp, *bUV;
    float *ag, *bjp, *hw1, *hw2;
    float *outp, *outs;
};

__global__ __launch_bounds__(NTHR) void k_mega(Params P){
    cg::grid_group grid = cg::this_grid();
    const int tid = threadIdx.x, blk = blockIdx.x;
    const int gid = blk * NTHR + tid;
    __shared__ float LP[6656];          // 26.6 KB, reused across phases

    // ---- phase 0: zero the atomic buffers ----
    if (gid < N_NODES){ P.deg[gid] = 0.f; P.cnt[gid] = 0; P.fill[gid] = 0; }
    grid.sync();

    // ---- phase 1: degree + in-edge counts ----
    if (gid < N_EDGES){
        int d = P.ei[N_EDGES + gid];
        atomicAdd(&P.deg[d], P.ew[gid]);
        atomicAdd(&P.cnt[d], 1);
    }
    grid.sync();

    // ---- phase 2: rowptr scan (blk0) | combined gate weights (blk1/2) | dinv (blk3) ----
    if (blk == 0){
        int* sc = (int*)LP;
        int base = tid * 4;
        int c0 = P.cnt[base], c1 = P.cnt[base+1], c2 = P.cnt[base+2], c3 = P.cnt[base+3];
        int ts = c0 + c1 + c2 + c3;
        sc[tid] = ts;
        __syncthreads();
        for (int off = 1; off < NTHR; off <<= 1){
            int v = (tid >= off) ? sc[tid - off] : 0;
            __syncthreads();
            sc[tid] += v;
            __syncthreads();
        }
        int exc = sc[tid] - ts;
        P.rowptr[base]   = exc;
        P.rowptr[base+1] = exc + c0;
        P.rowptr[base+2] = exc + c0 + c1;
        P.rowptr[base+3] = exc + c0 + c1 + c2;
        if (tid == NTHR-1) P.rowptr[N_NODES] = sc[tid];
    } else if (blk == 1 || blk == 2){
        const float* Wc = (blk == 1) ? P.Wcz : P.Wch;
        const float* Wl = (blk == 1) ? P.Wlz : P.Wlh;
        const float* bc = (blk == 1) ? P.bcz : P.bch;
        const float* bl = (blk == 1) ? P.blz : P.blh;
        float* Wp = (blk == 1) ? P.Wzp : P.Whp;
        for (int idx = tid; idx < IN_F*HID; idx += NTHR){
            int i = idx >> 6, f = idx & 63;
            float s = 0.f;
            for (int k = 0; k < HID; ++k) s += Wc[i*HID+k] * Wl[k*HID+f];
            Wp[idx] = s;
        }
        if (tid < HID){
            float s = bl[tid];
            for (int k = 0; k < HID; ++k) s += bc[k] * Wl[k*HID+tid];
            P.bUV[(blk-1)*HID + tid] = s;
        }
    } else if (blk == 3){
        int base = tid * 4;
        #pragma unroll
        for (int k = 0; k < 4; ++k){
            int i = base + k;
            float di = 1.f / sqrtf(P.deg[i] + 1.f);
            P.dinv[i] = di; P.dself[i] = di * di;
        }
    }
    grid.sync();

    // ---- phase 3: CSR fill + per-edge norm ----
    if (gid < N_EDGES){
        int s = P.ei[gid], d = P.ei[N_EDGES + gid];
        int pos = P.rowptr[d] + atomicAdd(&P.fill[d], 1);
        P.csrc[pos] = s;
        P.cnrm[pos] = P.dinv[s] * P.ew[gid] * P.dinv[d];
    }
    grid.sync();

    // ---- phase 4: fused aggX (in LDS) -> gates -> Wred -> emb -> 3 emb-products ----
    {
        float* part = LP;          // 16 slots x 5 t x 32 f = 2560
        float* axs  = LP + 2560;   // 5 x 32
        float* hs   = LP + 2720;   // 5 x 64
        float* pw   = LP + 3040;   // 5 x 64
        float* hemb = LP + 3360;   // 64
        const int slot = tid >> 5, f5 = tid & 31;   // 16 edge slots x 32 features
        const int f = tid & 63, t = tid >> 6;       // 8 waves: 0..4 used for gates
        for (int rep = 0; rep < 8; ++rep){
            int n = (rep << 8) + blk;
            __syncthreads();
            int beg = P.rowptr[n], end = P.rowptr[n+1];
            float a0=0.f, a1=0.f, a2=0.f, a3=0.f, a4=0.f;
            for (int p = beg + slot; p < end; p += 16){
                int s = P.csrc[p]; float c = P.cnrm[p];
                a0 += c * P.x[(0*N_NODES + s)*IN_F + f5];
                a1 += c * P.x[(1*N_NODES + s)*IN_F + f5];
                a2 += c * P.x[(2*N_NODES + s)*IN_F + f5];
                a3 += c * P.x[(3*N_NODES + s)*IN_F + f5];
                a4 += c * P.x[(4*N_NODES + s)*IN_F + f5];
            }
            part[(slot*SEQL + 0)*IN_F + f5] = a0;
            part[(slot*SEQL + 1)*IN_F + f5] = a1;
            part[(slot*SEQL + 2)*IN_F + f5] = a2;
            part[(slot*SEQL + 3)*IN_F + f5] = a3;
            part[(slot*SEQL + 4)*IN_F + f5] = a4;
            __syncthreads();
            if (tid < SEQL*IN_F){
                int tt = tid >> 5, ff = tid & 31;
                float s = P.dself[n] * P.x[(tt*N_NODES + n)*IN_F + ff];
                #pragma unroll
                for (int sl = 0; sl < 16; ++sl) s += part[(sl*SEQL + tt)*IN_F + ff];
                axs[tt*IN_F + ff] = s;
            }
            __syncthreads();
            if (t < SEQL){
                float zz = P.bUV[f], hh = P.bUV[HID + f];
                #pragma unroll
                for (int i = 0; i < IN_F; ++i){
                    float a = axs[t*IN_F + i];          // wave-uniform broadcast
                    zz += a * P.Wzp[i*HID + f];
                    hh += a * P.Whp[i*HID + f];
                }
                float z = 1.f / (1.f + expf(-zz));
                hs[t*HID + f] = (1.f - z) * tanhf(hh);
            }
            __syncthreads();
            if (t < SEQL){
                float pp = 0.f;
                #pragma unroll
                for (int k = 0; k < HID; ++k) pp += hs[t*HID + k] * P.Wred[(t*HID + k)*HID + f];
                pw[t*HID + f] = pp;
            }
            __syncthreads();
            if (tid < HID){
                float hr = P.bred[tid];
                #pragma unroll
                for (int t2 = 0; t2 < SEQL; ++t2) hr += pw[t2*HID + tid];
                hemb[tid] = hr;
            }
            __syncthreads();
            if (t < 3){
                const float* W = (t == 0) ? P.Wi1 : (t == 1) ? (P.Wi1 + HID*HID) : P.Wc1;
                float acc = (t == 1) ? P.bi1[f] : 0.f;
                #pragma unroll
                for (int k = 0; k < HID; ++k) acc += hemb[k] * W[k*HID + f];
                float* O = (t == 0) ? P.ag : (t == 1) ? P.bjp : P.hw1;
                O[n*HID + f] = acc;                     // bjp has bi1 folded in
            }
        }
    }
    grid.sync();

    // ---- phase 5: gcn1 + LN + relu + premultiply Wc2 ----
    {
        float* red8 = LP;          // 8 x 64
        float* hsh  = LP + 512;    // 64
        const int f = tid & 63, w = tid >> 6;
        for (int rep = 0; rep < 8; ++rep){
            int n = (rep << 8) + blk;
            __syncthreads();
            int beg = P.rowptr[n], end = P.rowptr[n+1];
            float agg = 0.f;
            for (int p = beg + w; p < end; p += 8) agg += P.cnrm[p] * P.hw1[P.csrc[p]*HID + f];
            red8[w*HID + f] = agg;
            __syncthreads();
            if (w == 0){
                float g = P.bc1[f] + P.dself[n] * P.hw1[n*HID + f];
                #pragma unroll
                for (int k = 0; k < 8; ++k) g += red8[k*HID + f];
                float sum = g;
                for (int o = 32; o > 0; o >>= 1) sum += __shfl_xor(sum, o, 64);
                float mu = sum * (1.f/64.f);
                float d = g - mu;
                float vs = d * d;
                for (int o = 32; o > 0; o >>= 1) vs += __shfl_xor(vs, o, 64);
                float var = vs * (1.f/64.f);
                float h = d * (1.f / sqrtf(var + LN_EPS)) * P.g1[f] + P.be1[f];
                hsh[f] = fmaxf(h, 0.f);
            }
            __syncthreads();
            float s = 0.f;
            #pragma unroll
            for (int k = 0; k < 8; ++k) s += hsh[w*8 + k] * P.Wc2[(w*8 + k)*HID + f];
            red8[w*HID + f] = s;
            __syncthreads();
            if (w == 0){
                float o = 0.f;
                #pragma unroll
                for (int k = 0; k < 8; ++k) o += red8[k*HID + f];
                P.hw2[n*HID + f] = o;
            }
        }
    }
    grid.sync();

    // ---- phase 6: gcn2 + LN + relu + node_pred, then scores (dep: phase-4 barrier) ----
    {
        float* red8 = LP;
        float* hsh  = LP + 512;
        const int f = tid & 63, w = tid >> 6;
        for (int rep = 0; rep < 8; ++rep){
            int n = (rep << 8) + blk;
            __syncthreads();
            int beg = P.rowptr[n], end = P.rowptr[n+1];
            float agg = 0.f;
            for (int p = beg + w; p < end; p += 8) agg += P.cnrm[p] * P.hw2[P.csrc[p]*HID + f];
            red8[w*HID + f] = agg;
            __syncthreads();
            if (w == 0){
                float g = P.bc2[f] + P.dself[n] * P.hw2[n*HID + f];
                #pragma unroll
                for (int k = 0; k < 8; ++k) g += red8[k*HID + f];
                float sum = g;
                for (int o = 32; o > 0; o >>= 1) sum += __shfl_xor(sum, o, 64);
                float mu = sum * (1.f/64.f);
                float d = g - mu;
                float vs = d * d;
                for (int o = 32; o > 0; o >>= 1) vs += __shfl_xor(vs, o, 64);
                float var = vs * (1.f/64.f);
                float h = d * (1.f / sqrtf(var + LN_EPS)) * P.g2[f] + P.be2[f];
                hsh[f] = fmaxf(h, 0.f);
            }
            __syncthreads();
            if (w == 0 && f < OUT_F){
                float s = P.bout[f];
                #pragma unroll
                for (int k = 0; k < HID; ++k) s += hsh[k] * P.Wout[k*OUT_F + f];
                P.outp[n*OUT_F + f] = s;
            }
        }
    }
    // scores: 2048 tiles of 32i x 64j; depends only on ag/bjp (ready since phase-4 sync)
    {
        float* bs = LP;            // 64 x 68
        float* as = LP + 4352;     // 32 x 68
        float* wv = LP + 6528;     // 64
        const int tj = tid & 63, w = tid >> 6;
        float b2v = P.bi2[0];
        for (int rep = 0; rep < 8; ++rep){
            int tl = (rep << 8) + blk;
            int i0 = (tl >> 5) * 32, j0 = (tl & 31) * 64;
            __syncthreads();
            for (int idx = tid; idx < 1024; idx += NTHR){
                int jj = idx >> 4, c = idx & 15;
                *(float4*)&bs[jj*68 + c*4] = *(const float4*)&P.bjp[(j0 + jj)*HID + c*4];
            }
            {
                int ii = tid >> 4, c = tid & 15;
                *(float4*)&as[ii*68 + c*4] = *(const float4*)&P.ag[(i0 + ii)*HID + c*4];
            }
            if (tid < 64) wv[tid] = P.Wi2[tid];
            __syncthreads();
            float acc0 = 0.f, acc1 = 0.f, acc2 = 0.f, acc3 = 0.f;
            #pragma unroll
            for (int c = 0; c < 16; ++c){
                float4 bv = *(float4*)&bs[tj*68 + c*4];
                float4 w4 = *(float4*)&wv[c*4];
                float4 r0 = *(float4*)&as[(w*4 + 0)*68 + c*4];
                float4 r1 = *(float4*)&as[(w*4 + 1)*68 + c*4];
                float4 r2 = *(float4*)&as[(w*4 + 2)*68 + c*4];
                float4 r3 = *(float4*)&as[(w*4 + 3)*68 + c*4];
                acc0 += fmaxf(r0.x+bv.x,0.f)*w4.x + fmaxf(r0.y+bv.y,0.f)*w4.y
                      + fmaxf(r0.z+bv.z,0.f)*w4.z + fmaxf(r0.w+bv.w,0.f)*w4.w;
                acc1 += fmaxf(r1.x+bv.x,0.f)*w4.x + fmaxf(r1.y+bv.y,0.f)*w4.y
                      + fmaxf(r1.z+bv.z,0.f)*w4.z + fmaxf(r1.w+bv.w,0.f)*w4.w;
                acc2 += fmaxf(r2.x+bv.x,0.f)*w4.x + fmaxf(r2.y+bv.y,0.f)*w4.y
                      + fmaxf(r2.z+bv.z,0.f)*w4.z + fmaxf(r2.w+bv.w,0.f)*w4.w;
                acc3 += fmaxf(r3.x+bv.x,0.f)*w4.x + fmaxf(r3.y+bv.y,0.f)*w4.y
                      + fmaxf(r3.z+bv.z,0.f)*w4.z + fmaxf(r3.w+bv.w,0.f)*w4.w;
            }
            long ro = (long)(i0 + w*4) * N_NODES + j0 + tj;
            P.outs[ro               ] = acc0 + b2v;
            P.outs[ro +     N_NODES ] = acc1 + b2v;
            P.outs[ro + 2L* N_NODES ] = acc2 + b2v;
            P.outs[ro + 3L* N_NODES ] = acc3 + b2v;
        }
    }
}

extern "C" void kernel_launch(void* const* d_in, const int* in_sizes, int n_in,
                              void* d_out, int out_size, void* d_ws, size_t ws_size,
                              hipStream_t stream){
    Params P;
    P.x   = (const float*)d_in[0];
    P.ew  = (const float*)d_in[1];
    P.Wcz = (const float*)d_in[2];  P.bcz = (const float*)d_in[3];
    P.Wlz = (const float*)d_in[4];  P.blz = (const float*)d_in[5];
    // d_in[6..9]: Wcr/bcr/Wlr/blr — dead code (H=0 so reset gate has no effect)
    P.Wch = (const float*)d_in[10]; P.bch = (const float*)d_in[11];
    P.Wlh = (const float*)d_in[12]; P.blh = (const float*)d_in[13];
    P.Wred= (const float*)d_in[14]; P.bred= (const float*)d_in[15];
    P.Wc1 = (const float*)d_in[16]; P.bc1 = (const float*)d_in[17];
    P.Wc2 = (const float*)d_in[18]; P.bc2 = (const float*)d_in[19];
    P.g1  = (const float*)d_in[20]; P.be1 = (const float*)d_in[21];
    P.g2  = (const float*)d_in[22]; P.be2 = (const float*)d_in[23];
    P.Wout= (const float*)d_in[24]; P.bout= (const float*)d_in[25];
    P.Wi1 = (const float*)d_in[26]; P.bi1 = (const float*)d_in[27];
    P.Wi2 = (const float*)d_in[28]; P.bi2 = (const float*)d_in[29];
    P.ei  = (const int*)d_in[30];

    float* w = (float*)d_ws;            // offsets in floats; all 16B-aligned
    P.deg    = w;            // 2048
    P.cnt    = (int*)(w + 2048);        // 2048
    P.fill   = (int*)(w + 4096);        // 2048
    P.rowptr = (int*)(w + 6144);        // 2049 (pad to 2560)
    P.dinv   = w + 8704;                // 2048
    P.dself  = w + 10752;               // 2048
    P.csrc   = (int*)(w + 12800);       // 65536
    P.cnrm   = w + 78336;               // 65536
    P.Wzp    = w + 143872;              // 2048
    P.Whp    = w + 145920;              // 2048
    P.bUV    = w + 147968;              // 128
    P.ag     = w + 148096;              // 131072
    P.bjp    = w + 279168;              // 131072
    P.hw1    = w + 410240;              // 131072
    P.hw2    = w + 541312;              // 131072
    P.outp   = (float*)d_out;
    P.outs   = (float*)d_out + N_NODES*OUT_F;

    void* args[] = { &P };
    hipLaunchCooperativeKernel((const void*)k_mega, dim3(NBLK), dim3(NTHR),
                               args, 0, stream);
}

// Round 6
// 287.995 us; speedup vs baseline: 2.8228x; 2.8228x over previous
//
#include <hip/hip_runtime.h>
#include <math.h>

#define N_NODES 2048
#define N_EDGES 65536
#define SEQL 5
#define IN_F 32
#define HID 64
#define OUT_F 16
#define LN_EPS 1e-5f

// ================= k_setup: 4 blocks x 1024 =================
// blk0: LDS histogram (cnt,deg) -> scan -> rowptr, dinv, dself
// blk1/2: combined gate weights Wzp/Whp + bUV
// blk3: zero fill[]
__global__ __launch_bounds__(1024) void k_setup(
        const int* __restrict__ ei, const float* __restrict__ ew,
        const float* __restrict__ Wcz, const float* __restrict__ Wlz,
        const float* __restrict__ bcz, const float* __restrict__ blz,
        const float* __restrict__ Wch, const float* __restrict__ Wlh,
        const float* __restrict__ bch, const float* __restrict__ blh,
        int* __restrict__ rowptr, float* __restrict__ dinv, float* __restrict__ dself,
        int* __restrict__ fill,
        float* __restrict__ Wzp, float* __restrict__ Whp, float* __restrict__ bUV){
    int b = blockIdx.x, t = threadIdx.x;
    if (b == 0){
        __shared__ int   hist[N_NODES];
        __shared__ float degs[N_NODES];
        __shared__ int   sc[1024];
        hist[t] = 0; hist[t + 1024] = 0;
        degs[t] = 0.f; degs[t + 1024] = 0.f;
        __syncthreads();
        #pragma unroll 4
        for (int i = 0; i < 64; ++i){
            int e = t + i*1024;
            int d = ei[N_EDGES + e];
            atomicAdd(&hist[d], 1);
            atomicAdd(&degs[d], ew[e]);
        }
        __syncthreads();
        int c0 = hist[2*t], c1 = hist[2*t+1];
        int ts = c0 + c1;
        sc[t] = ts;
        __syncthreads();
        for (int off = 1; off < 1024; off <<= 1){
            int v = (t >= off) ? sc[t - off] : 0;
            __syncthreads();
            sc[t] += v;
            __syncthreads();
        }
        int exc = sc[t] - ts;
        rowptr[2*t]   = exc;
        rowptr[2*t+1] = exc + c0;
        if (t == 1023) rowptr[N_NODES] = sc[t];
        float i0 = 1.f / sqrtf(degs[2*t] + 1.f);
        float i1 = 1.f / sqrtf(degs[2*t+1] + 1.f);
        dinv[2*t] = i0;   dinv[2*t+1] = i1;
        dself[2*t] = i0*i0; dself[2*t+1] = i1*i1;
    } else if (b == 1 || b == 2){
        const float* Wc = (b == 1) ? Wcz : Wch;
        const float* Wl = (b == 1) ? Wlz : Wlh;
        const float* bc = (b == 1) ? bcz : bch;
        const float* bl = (b == 1) ? blz : blh;
        float* Wp = (b == 1) ? Wzp : Whp;
        for (int idx = t; idx < IN_F*HID; idx += 1024){
            int i = idx >> 6, f = idx & 63;
            float s = 0.f;
            for (int k = 0; k < HID; ++k) s += Wc[i*HID+k] * Wl[k*HID+f];
            Wp[idx] = s;
        }
        if (t < HID){
            float s = bl[t];
            for (int k = 0; k < HID; ++k) s += bc[k] * Wl[k*HID+t];
            bUV[(b-1)*HID + t] = s;
        }
    } else {
        if (t < N_NODES/2){ fill[2*t] = 0; fill[2*t+1] = 0; }
    }
}

// ================= CSR fill + per-edge norm =================
__global__ void k_csr(const int* __restrict__ ei, const float* __restrict__ ew,
                      const float* __restrict__ dinv, const int* __restrict__ rowptr,
                      int* __restrict__ fill, int* __restrict__ csrc, float* __restrict__ cnrm){
    int e = blockIdx.x * 256 + threadIdx.x;
    if (e < N_EDGES){
        int s = ei[e], d = ei[N_EDGES + e];
        int pos = rowptr[d] + atomicAdd(&fill[d], 1);
        csrc[pos] = s;
        cnrm[pos] = dinv[s] * ew[e] * dinv[d];
    }
}

// ================= fused: aggX(LDS) -> gates -> Wred -> emb -> 3 products =================
__global__ __launch_bounds__(320) void k_gate(const float* __restrict__ x,
        const float* __restrict__ dself, const int* __restrict__ rowptr,
        const int* __restrict__ csrc, const float* __restrict__ cnrm,
        const float* __restrict__ bUV, const float* __restrict__ Wzp, const float* __restrict__ Whp,
        const float* __restrict__ Wred, const float* __restrict__ bred,
        const float* __restrict__ Wi1, const float* __restrict__ bi1, const float* __restrict__ Wc1,
        float* __restrict__ ag, float* __restrict__ bjp, float* __restrict__ hw1){
    int n = blockIdx.x;
    int tid = threadIdx.x;
    __shared__ float part[10][SEQL][IN_F];   // 10 edge slots
    __shared__ float axs[SEQL][IN_F];
    __shared__ float hs[SEQL][HID];
    __shared__ float pw[SEQL][HID];
    __shared__ float hemb[HID];
    const int slot = tid >> 5, f5 = tid & 31;   // 10 x 32
    const int f = tid & 63, t = tid >> 6;       // 5 waves
    int beg = rowptr[n], end = rowptr[n+1];
    float a0=0.f, a1=0.f, a2=0.f, a3=0.f, a4=0.f;
    for (int p = beg + slot; p < end; p += 10){
        int s = csrc[p]; float c = cnrm[p];
        a0 += c * x[(0*N_NODES + s)*IN_F + f5];
        a1 += c * x[(1*N_NODES + s)*IN_F + f5];
        a2 += c * x[(2*N_NODES + s)*IN_F + f5];
        a3 += c * x[(3*N_NODES + s)*IN_F + f5];
        a4 += c * x[(4*N_NODES + s)*IN_F + f5];
    }
    part[slot][0][f5] = a0;
    part[slot][1][f5] = a1;
    part[slot][2][f5] = a2;
    part[slot][3][f5] = a3;
    part[slot][4][f5] = a4;
    __syncthreads();
    if (tid < SEQL*IN_F){
        int tt = tid >> 5, ff = tid & 31;
        float s = dself[n] * x[(tt*N_NODES + n)*IN_F + ff];
        #pragma unroll
        for (int sl = 0; sl < 10; ++sl) s += part[sl][tt][ff];
        axs[tt][ff] = s;
    }
    __syncthreads();
    {   // all 5 waves: gate for timestep t
        float zz = bUV[f], hh = bUV[HID + f];
        #pragma unroll
        for (int i = 0; i < IN_F; ++i){
            float a = axs[t][i];                 // wave-uniform LDS broadcast
            zz += a * Wzp[i*HID + f];
            hh += a * Whp[i*HID + f];
        }
        float z = 1.f / (1.f + expf(-zz));
        hs[t][f] = (1.f - z) * tanhf(hh);
    }
    __syncthreads();
    {   float pp = 0.f;
        #pragma unroll
        for (int k = 0; k < HID; ++k) pp += hs[t][k] * Wred[(t*HID + k)*HID + f];
        pw[t][f] = pp;
    }
    __syncthreads();
    if (tid < HID){
        float hr = bred[tid];
        #pragma unroll
        for (int t2 = 0; t2 < SEQL; ++t2) hr += pw[t2][tid];
        hemb[tid] = hr;
    }
    __syncthreads();
    if (t < 3){
        const float* W = (t == 0) ? Wi1 : (t == 1) ? (Wi1 + HID*HID) : Wc1;
        float acc = (t == 1) ? bi1[f] : 0.f;
        #pragma unroll
        for (int k = 0; k < HID; ++k) acc += hemb[k] * W[k*HID + f];
        float* O = (t == 0) ? ag : (t == 1) ? bjp : hw1;
        O[n*HID + f] = acc;                      // bjp has bi1 folded in
    }
}

// ================= gcn1: 4 waves split edges, LN+relu, premultiply Wc2 =================
__global__ __launch_bounds__(256) void k_gcn1(
                       const float* __restrict__ hw1, const float* __restrict__ dself,
                       const int* __restrict__ rowptr, const int* __restrict__ csrc, const float* __restrict__ cnrm,
                       const float* __restrict__ bc1, const float* __restrict__ g1, const float* __restrict__ be1,
                       const float* __restrict__ Wc2, float* __restrict__ hw2){
    int n = blockIdx.x;
    int f = threadIdx.x & 63;
    int w = threadIdx.x >> 6;
    int beg = rowptr[n], end = rowptr[n+1];
    __shared__ float red[4][HID];
    __shared__ float hsh[HID];
    float agg = 0.f;
    for (int p = beg + w; p < end; p += 4) agg += cnrm[p] * hw1[csrc[p]*HID + f];
    red[w][f] = agg;
    __syncthreads();
    if (w == 0){
        float g = red[0][f] + red[1][f] + red[2][f] + red[3][f]
                + dself[n] * hw1[n*HID + f] + bc1[f];
        float sum = g;
        for (int o = 32; o > 0; o >>= 1) sum += __shfl_xor(sum, o, 64);
        float mu = sum * (1.f/64.f);
        float d = g - mu;
        float vs = d * d;
        for (int o = 32; o > 0; o >>= 1) vs += __shfl_xor(vs, o, 64);
        float var = vs * (1.f/64.f);
        float h = d * (1.f / sqrtf(var + LN_EPS)) * g1[f] + be1[f];
        hsh[f] = fmaxf(h, 0.f);
    }
    __syncthreads();
    float s = 0.f;
    #pragma unroll
    for (int k = 0; k < 16; ++k) s += hsh[w*16 + k] * Wc2[(w*16 + k)*HID + f];
    red[w][f] = s;
    __syncthreads();
    if (w == 0) hw2[n*HID + f] = red[0][f] + red[1][f] + red[2][f] + red[3][f];
}

// ================= gcn2: 4 waves split edges, LN+relu, node_pred out =================
__global__ __launch_bounds__(256) void k_gcn2(
                       const float* __restrict__ hw2, const float* __restrict__ dself,
                       const int* __restrict__ rowptr, const int* __restrict__ csrc, const float* __restrict__ cnrm,
                       const float* __restrict__ bc2, const float* __restrict__ g2, const float* __restrict__ be2,
                       const float* __restrict__ Wout, const float* __restrict__ bout, float* __restrict__ outp){
    int n = blockIdx.x;
    int f = threadIdx.x & 63;
    int w = threadIdx.x >> 6;
    int beg = rowptr[n], end = rowptr[n+1];
    __shared__ float red[4][HID];
    __shared__ float hsh[HID];
    float agg = 0.f;
    for (int p = beg + w; p < end; p += 4) agg += cnrm[p] * hw2[csrc[p]*HID + f];
    red[w][f] = agg;
    __syncthreads();
    if (w == 0){
        float g = red[0][f] + red[1][f] + red[2][f] + red[3][f]
                + dself[n] * hw2[n*HID + f] + bc2[f];
        float sum = g;
        for (int o = 32; o > 0; o >>= 1) sum += __shfl_xor(sum, o, 64);
        float mu = sum * (1.f/64.f);
        float d = g - mu;
        float vs = d * d;
        for (int o = 32; o > 0; o >>= 1) vs += __shfl_xor(vs, o, 64);
        float var = vs * (1.f/64.f);
        float h = d * (1.f / sqrtf(var + LN_EPS)) * g2[f] + be2[f];
        hsh[f] = fmaxf(h, 0.f);
    }
    __syncthreads();
    if (w == 0 && f < OUT_F){
        float s = bout[f];
        #pragma unroll
        for (int k = 0; k < HID; ++k) s += hsh[k] * Wout[k*OUT_F + f];
        outp[n*OUT_F + f] = s;
    }
}

// ================= scores: stride-65 LDS (conflict-free), wave-uniform a s_loads =================
__global__ __launch_bounds__(256) void k_scores(const float* __restrict__ ag, const float* __restrict__ bjp,
                         const float* __restrict__ Wi2, const float* __restrict__ bi2,
                         float* __restrict__ outs){
    __shared__ float bs[64*65];
    __shared__ float wv[64];
    int tid = threadIdx.x;
    int j0 = blockIdx.x * 64;
    int i0 = blockIdx.y * 16;
    for (int idx = tid; idx < 4096; idx += 256){
        int jj = idx >> 6, f = idx & 63;
        bs[jj*65 + f] = bjp[(j0 + jj)*HID + f];
    }
    if (tid < 64) wv[tid] = Wi2[tid];
    __syncthreads();
    int tj = tid & 63;
    int w = __builtin_amdgcn_readfirstlane(tid >> 6);   // wave-uniform -> scalar a-loads
    const float* ar = ag + (i0 + w*4)*HID;
    float bi2v = bi2[0];
    float acc0 = 0.f, acc1 = 0.f, acc2 = 0.f, acc3 = 0.f;
    #pragma unroll
    for (int f = 0; f < 64; ++f){
        float bv = bs[tj*65 + f];
        float wf = wv[f];
        acc0 += fmaxf(ar[       f] + bv, 0.f) * wf;
        acc1 += fmaxf(ar[ 64 +  f] + bv, 0.f) * wf;
        acc2 += fmaxf(ar[128 +  f] + bv, 0.f) * wf;
        acc3 += fmaxf(ar[192 +  f] + bv, 0.f) * wf;
    }
    long ro = (long)(i0 + w*4) * N_NODES + j0 + tj;
    outs[ro                ] = acc0 + bi2v;
    outs[ro +     N_NODES  ] = acc1 + bi2v;
    outs[ro + 2L* N_NODES  ] = acc2 + bi2v;
    outs[ro + 3L* N_NODES  ] = acc3 + bi2v;
}

extern "C" void kernel_launch(void* const* d_in, const int* in_sizes, int n_in,
                              void* d_out, int out_size, void* d_ws, size_t ws_size,
                              hipStream_t stream){
    const float* x   = (const float*)d_in[0];
    const float* ew  = (const float*)d_in[1];
    const float* Wcz = (const float*)d_in[2];  const float* bcz = (const float*)d_in[3];
    const float* Wlz = (const float*)d_in[4];  const float* blz = (const float*)d_in[5];
    // d_in[6..9]: Wcr/bcr/Wlr/blr — dead code (H=0 so reset gate has no effect)
    const float* Wch = (const float*)d_in[10]; const float* bch = (const float*)d_in[11];
    const float* Wlh = (const float*)d_in[12]; const float* blh = (const float*)d_in[13];
    const float* Wred= (const float*)d_in[14]; const float* bred= (const float*)d_in[15];
    const float* Wc1 = (const float*)d_in[16]; const float* bc1 = (const float*)d_in[17];
    const float* Wc2 = (const float*)d_in[18]; const float* bc2 = (const float*)d_in[19];
    const float* g1  = (const float*)d_in[20]; const float* be1 = (const float*)d_in[21];
    const float* g2  = (const float*)d_in[22]; const float* be2 = (const float*)d_in[23];
    const float* Wout= (const float*)d_in[24]; const float* bout= (const float*)d_in[25];
    const float* Wi1 = (const float*)d_in[26]; const float* bi1 = (const float*)d_in[27];
    const float* Wi2 = (const float*)d_in[28]; const float* bi2 = (const float*)d_in[29];
    const int*  ei  = (const int*)d_in[30];

    float* w = (float*)d_ws;            // float offsets, all 16B aligned
    int*   rowptr = (int*)w;            // 2049 (pad 2560)
    float* dinv   = w + 2560;           // 2048
    float* dself  = w + 4608;           // 2048
    int*   fill   = (int*)(w + 6656);   // 2048
    int*   csrc   = (int*)(w + 8704);   // 65536
    float* cnrm   = w + 74240;          // 65536
    float* Wzp    = w + 139776;         // 2048
    float* Whp    = w + 141824;         // 2048
    float* bUV    = w + 143872;         // 128
    float* ag     = w + 144000;         // 131072
    float* bjp    = w + 275072;         // 131072
    float* hw1    = w + 406144;         // 131072
    float* hw2    = w + 537216;         // 131072

    k_setup<<<4, 1024, 0, stream>>>(ei, ew, Wcz, Wlz, bcz, blz, Wch, Wlh, bch, blh,
                                    rowptr, dinv, dself, fill, Wzp, Whp, bUV);
    k_csr<<<N_EDGES/256, 256, 0, stream>>>(ei, ew, dinv, rowptr, fill, csrc, cnrm);
    k_gate<<<N_NODES, 320, 0, stream>>>(x, dself, rowptr, csrc, cnrm, bUV, Wzp, Whp,
                                        Wred, bred, Wi1, bi1, Wc1, ag, bjp, hw1);
    k_gcn1<<<N_NODES, 256, 0, stream>>>(hw1, dself, rowptr, csrc, cnrm, bc1, g1, be1, Wc2, hw2);
    k_gcn2<<<N_NODES, 256, 0, stream>>>(hw2, dself, rowptr, csrc, cnrm, bc2, g2, be2, Wout, bout,
                                        (float*)d_out);
    dim3 sg(N_NODES/64, N_NODES/16);
    k_scores<<<sg, 256, 0, stream>>>(ag, bjp, Wi2, bi2, (float*)d_out + N_NODES*OUT_F);
}

// Round 7
// 221.664 us; speedup vs baseline: 3.6674x; 1.2992x over previous
//
#include <hip/hip_runtime.h>
#include <math.h>

#define N_NODES 2048
#define N_EDGES 65536
#define SEQL 5
#define IN_F 32
#define HID 64
#define OUT_F 16
#define LN_EPS 1e-5f

// ================= k_deg_wcomb: 258 blocks x 256 =================
// blocks 0..255: edge scatter (global atomics, 256 CUs wide)
// block 256: Wzp = Wcz@Wlz[:64] + bUV[0:64];  block 257: Whp/bUV[64:128]
__global__ __launch_bounds__(256) void k_deg_wcomb(
        const int* __restrict__ ei, const float* __restrict__ ew,
        const float* __restrict__ Wcz, const float* __restrict__ Wlz,
        const float* __restrict__ bcz, const float* __restrict__ blz,
        const float* __restrict__ Wch, const float* __restrict__ Wlh,
        const float* __restrict__ bch, const float* __restrict__ blh,
        float* __restrict__ deg, int* __restrict__ cnt,
        float* __restrict__ Wzp, float* __restrict__ Whp, float* __restrict__ bUV){
    int b = blockIdx.x, t = threadIdx.x;
    if (b < 256){
        int e = b * 256 + t;
        int d = ei[N_EDGES + e];
        atomicAdd(&deg[d], ew[e]);
        atomicAdd(&cnt[d], 1);
    } else {
        const float* Wc = (b == 256) ? Wcz : Wch;
        const float* Wl = (b == 256) ? Wlz : Wlh;
        const float* bc = (b == 256) ? bcz : bch;
        const float* bl = (b == 256) ? blz : blh;
        float* Wp = (b == 256) ? Wzp : Whp;
        for (int idx = t; idx < IN_F*HID; idx += 256){
            int i = idx >> 6, f = idx & 63;
            float s = 0.f;
            #pragma unroll 8
            for (int k = 0; k < HID; ++k) s += Wc[i*HID+k] * Wl[k*HID+f];
            Wp[idx] = s;
        }
        if (t < HID){
            float s = bl[t];
            for (int k = 0; k < HID; ++k) s += bc[k] * Wl[k*HID+t];
            bUV[(b-256)*HID + t] = s;
        }
    }
}

// ================= k_scan: 1 block x 1024 — rowptr scan + dinv/dself + zero fill =================
__global__ __launch_bounds__(1024) void k_scan(
        const float* __restrict__ deg, const int* __restrict__ cnt,
        int* __restrict__ rowptr, float* __restrict__ dinv, float* __restrict__ dself,
        int* __restrict__ fill){
    __shared__ int sc[1024];
    int t = threadIdx.x;
    int c0 = cnt[2*t], c1 = cnt[2*t+1];
    int ts = c0 + c1;
    sc[t] = ts;
    __syncthreads();
    for (int off = 1; off < 1024; off <<= 1){
        int v = (t >= off) ? sc[t - off] : 0;
        __syncthreads();
        sc[t] += v;
        __syncthreads();
    }
    int exc = sc[t] - ts;
    rowptr[2*t]   = exc;
    rowptr[2*t+1] = exc + c0;
    if (t == 1023) rowptr[N_NODES] = sc[t];
    float i0 = 1.f / sqrtf(deg[2*t] + 1.f);
    float i1 = 1.f / sqrtf(deg[2*t+1] + 1.f);
    dinv[2*t] = i0;     dinv[2*t+1] = i1;
    dself[2*t] = i0*i0; dself[2*t+1] = i1*i1;
    fill[2*t] = 0;      fill[2*t+1] = 0;
}

// ================= CSR fill + per-edge norm =================
__global__ void k_csr(const int* __restrict__ ei, const float* __restrict__ ew,
                      const float* __restrict__ dinv, const int* __restrict__ rowptr,
                      int* __restrict__ fill, int* __restrict__ csrc, float* __restrict__ cnrm){
    int e = blockIdx.x * 256 + threadIdx.x;
    if (e < N_EDGES){
        int s = ei[e], d = ei[N_EDGES + e];
        int pos = rowptr[d] + atomicAdd(&fill[d], 1);
        csrc[pos] = s;
        cnrm[pos] = dinv[s] * ew[e] * dinv[d];
    }
}

// ================= fused: aggX(LDS) -> gates -> Wred -> emb -> 3 products =================
__global__ __launch_bounds__(320) void k_gate(const float* __restrict__ x,
        const float* __restrict__ dself, const int* __restrict__ rowptr,
        const int* __restrict__ csrc, const float* __restrict__ cnrm,
        const float* __restrict__ bUV, const float* __restrict__ Wzp, const float* __restrict__ Whp,
        const float* __restrict__ Wred, const float* __restrict__ bred,
        const float* __restrict__ Wi1, const float* __restrict__ bi1, const float* __restrict__ Wc1,
        float* __restrict__ ag, float* __restrict__ bjp, float* __restrict__ hw1){
    int n = blockIdx.x;
    int tid = threadIdx.x;
    __shared__ float part[10][SEQL][IN_F];   // 10 edge slots
    __shared__ float axs[SEQL][IN_F];
    __shared__ float hs[SEQL][HID];
    __shared__ float pw[SEQL][HID];
    __shared__ float hemb[HID];
    const int slot = tid >> 5, f5 = tid & 31;   // 10 x 32
    const int f = tid & 63, t = tid >> 6;       // 5 waves
    int beg = rowptr[n], end = rowptr[n+1];
    float a0=0.f, a1=0.f, a2=0.f, a3=0.f, a4=0.f;
    for (int p = beg + slot; p < end; p += 10){
        int s = csrc[p]; float c = cnrm[p];
        a0 += c * x[(0*N_NODES + s)*IN_F + f5];
        a1 += c * x[(1*N_NODES + s)*IN_F + f5];
        a2 += c * x[(2*N_NODES + s)*IN_F + f5];
        a3 += c * x[(3*N_NODES + s)*IN_F + f5];
        a4 += c * x[(4*N_NODES + s)*IN_F + f5];
    }
    part[slot][0][f5] = a0;
    part[slot][1][f5] = a1;
    part[slot][2][f5] = a2;
    part[slot][3][f5] = a3;
    part[slot][4][f5] = a4;
    __syncthreads();
    if (tid < SEQL*IN_F){
        int tt = tid >> 5, ff = tid & 31;
        float s = dself[n] * x[(tt*N_NODES + n)*IN_F + ff];
        #pragma unroll
        for (int sl = 0; sl < 10; ++sl) s += part[sl][tt][ff];
        axs[tt][ff] = s;
    }
    __syncthreads();
    {   // all 5 waves: gate for timestep t
        float zz = bUV[f], hh = bUV[HID + f];
        #pragma unroll
        for (int i = 0; i < IN_F; ++i){
            float a = axs[t][i];                 // wave-uniform LDS broadcast
            zz += a * Wzp[i*HID + f];
            hh += a * Whp[i*HID + f];
        }
        float z = 1.f / (1.f + expf(-zz));
        hs[t][f] = (1.f - z) * tanhf(hh);
    }
    __syncthreads();
    {   float pp = 0.f;
        #pragma unroll
        for (int k = 0; k < HID; ++k) pp += hs[t][k] * Wred[(t*HID + k)*HID + f];
        pw[t][f] = pp;
    }
    __syncthreads();
    if (tid < HID){
        float hr = bred[tid];
        #pragma unroll
        for (int t2 = 0; t2 < SEQL; ++t2) hr += pw[t2][tid];
        hemb[tid] = hr;
    }
    __syncthreads();
    if (t < 3){
        const float* W = (t == 0) ? Wi1 : (t == 1) ? (Wi1 + HID*HID) : Wc1;
        float acc = (t == 1) ? bi1[f] : 0.f;
        #pragma unroll
        for (int k = 0; k < HID; ++k) acc += hemb[k] * W[k*HID + f];
        float* O = (t == 0) ? ag : (t == 1) ? bjp : hw1;
        O[n*HID + f] = acc;                      // bjp has bi1 folded in
    }
}

// ================= gcn1: 4 waves split edges, LN+relu, premultiply Wc2 =================
__global__ __launch_bounds__(256) void k_gcn1(
                       const float* __restrict__ hw1, const float* __restrict__ dself,
                       const int* __restrict__ rowptr, const int* __restrict__ csrc, const float* __restrict__ cnrm,
                       const float* __restrict__ bc1, const float* __restrict__ g1, const float* __restrict__ be1,
                       const float* __restrict__ Wc2, float* __restrict__ hw2){
    int n = blockIdx.x;
    int f = threadIdx.x & 63;
    int w = threadIdx.x >> 6;
    int beg = rowptr[n], end = rowptr[n+1];
    __shared__ float red[4][HID];
    __shared__ float hsh[HID];
    float agg = 0.f;
    for (int p = beg + w; p < end; p += 4) agg += cnrm[p] * hw1[csrc[p]*HID + f];
    red[w][f] = agg;
    __syncthreads();
    if (w == 0){
        float g = red[0][f] + red[1][f] + red[2][f] + red[3][f]
                + dself[n] * hw1[n*HID + f] + bc1[f];
        float sum = g;
        for (int o = 32; o > 0; o >>= 1) sum += __shfl_xor(sum, o, 64);
        float mu = sum * (1.f/64.f);
        float d = g - mu;
        float vs = d * d;
        for (int o = 32; o > 0; o >>= 1) vs += __shfl_xor(vs, o, 64);
        float var = vs * (1.f/64.f);
        float h = d * (1.f / sqrtf(var + LN_EPS)) * g1[f] + be1[f];
        hsh[f] = fmaxf(h, 0.f);
    }
    __syncthreads();
    float s = 0.f;
    #pragma unroll
    for (int k = 0; k < 16; ++k) s += hsh[w*16 + k] * Wc2[(w*16 + k)*HID + f];
    red[w][f] = s;
    __syncthreads();
    if (w == 0) hw2[n*HID + f] = red[0][f] + red[1][f] + red[2][f] + red[3][f];
}

// ================= gcn2 (blocks 0..2047) + scores (blocks 2048..6143) =================
__global__ __launch_bounds__(256) void k_gcn2s(
        const float* __restrict__ hw2, const float* __restrict__ dself,
        const int* __restrict__ rowptr, const int* __restrict__ csrc, const float* __restrict__ cnrm,
        const float* __restrict__ bc2, const float* __restrict__ g2, const float* __restrict__ be2,
        const float* __restrict__ Wout, const float* __restrict__ bout,
        const float* __restrict__ ag, const float* __restrict__ bjp,
        const float* __restrict__ Wi2, const float* __restrict__ bi2,
        float* __restrict__ outp, float* __restrict__ outs){
    int blk = blockIdx.x;
    int tid = threadIdx.x;
    if (blk < N_NODES){
        // ---- gcn2 + LN + relu + node_pred ----
        __shared__ float red[4][HID];
        __shared__ float hsh[HID];
        int n = blk;
        int f = tid & 63;
        int w = tid >> 6;
        int beg = rowptr[n], end = rowptr[n+1];
        float agg = 0.f;
        for (int p = beg + w; p < end; p += 4) agg += cnrm[p] * hw2[csrc[p]*HID + f];
        red[w][f] = agg;
        __syncthreads();
        if (w == 0){
            float g = red[0][f] + red[1][f] + red[2][f] + red[3][f]
                    + dself[n] * hw2[n*HID + f] + bc2[f];
            float sum = g;
            for (int o = 32; o > 0; o >>= 1) sum += __shfl_xor(sum, o, 64);
            float mu = sum * (1.f/64.f);
            float d = g - mu;
            float vs = d * d;
            for (int o = 32; o > 0; o >>= 1) vs += __shfl_xor(vs, o, 64);
            float var = vs * (1.f/64.f);
            float h = d * (1.f / sqrtf(var + LN_EPS)) * g2[f] + be2[f];
            hsh[f] = fmaxf(h, 0.f);
        }
        __syncthreads();
        if (w == 0 && f < OUT_F){
            float s = bout[f];
            #pragma unroll
            for (int k = 0; k < HID; ++k) s += hsh[k] * Wout[k*OUT_F + f];
            outp[n*OUT_F + f] = s;
        }
    } else {
        // ---- scores tile: 16 i x 64 j ----
        __shared__ float bs[64*65];
        __shared__ float wv[64];
        int tl = blk - N_NODES;
        int j0 = (tl & 31) * 64;
        int i0 = (tl >> 5) * 16;
        for (int idx = tid; idx < 4096; idx += 256){
            int jj = idx >> 6, f = idx & 63;
            bs[jj*65 + f] = bjp[(j0 + jj)*HID + f];
        }
        if (tid < 64) wv[tid] = Wi2[tid];
        __syncthreads();
        int tj = tid & 63;
        int w = __builtin_amdgcn_readfirstlane(tid >> 6);   // wave-uniform -> scalar a-loads
        const float* ar = ag + (i0 + w*4)*HID;
        float bi2v = bi2[0];
        float acc0 = 0.f, acc1 = 0.f, acc2 = 0.f, acc3 = 0.f;
        #pragma unroll
        for (int f = 0; f < 64; ++f){
            float bv = bs[tj*65 + f];
            float wf = wv[f];
            acc0 += fmaxf(ar[       f] + bv, 0.f) * wf;
            acc1 += fmaxf(ar[ 64 +  f] + bv, 0.f) * wf;
            acc2 += fmaxf(ar[128 +  f] + bv, 0.f) * wf;
            acc3 += fmaxf(ar[192 +  f] + bv, 0.f) * wf;
        }
        long ro = (long)(i0 + w*4) * N_NODES + j0 + tj;
        outs[ro                ] = acc0 + bi2v;
        outs[ro +     N_NODES  ] = acc1 + bi2v;
        outs[ro + 2L* N_NODES  ] = acc2 + bi2v;
        outs[ro + 3L* N_NODES  ] = acc3 + bi2v;
    }
}

extern "C" void kernel_launch(void* const* d_in, const int* in_sizes, int n_in,
                              void* d_out, int out_size, void* d_ws, size_t ws_size,
                              hipStream_t stream){
    const float* x   = (const float*)d_in[0];
    const float* ew  = (const float*)d_in[1];
    const float* Wcz = (const float*)d_in[2];  const float* bcz = (const float*)d_in[3];
    const float* Wlz = (const float*)d_in[4];  const float* blz = (const float*)d_in[5];
    // d_in[6..9]: Wcr/bcr/Wlr/blr — dead code (H=0 so reset gate has no effect)
    const float* Wch = (const float*)d_in[10]; const float* bch = (const float*)d_in[11];
    const float* Wlh = (const float*)d_in[12]; const float* blh = (const float*)d_in[13];
    const float* Wred= (const float*)d_in[14]; const float* bred= (const float*)d_in[15];
    const float* Wc1 = (const float*)d_in[16]; const float* bc1 = (const float*)d_in[17];
    const float* Wc2 = (const float*)d_in[18]; const float* bc2 = (const float*)d_in[19];
    const float* g1  = (const float*)d_in[20]; const float* be1 = (const float*)d_in[21];
    const float* g2  = (const float*)d_in[22]; const float* be2 = (const float*)d_in[23];
    const float* Wout= (const float*)d_in[24]; const float* bout= (const float*)d_in[25];
    const float* Wi1 = (const float*)d_in[26]; const float* bi1 = (const float*)d_in[27];
    const float* Wi2 = (const float*)d_in[28]; const float* bi2 = (const float*)d_in[29];
    const int*  ei  = (const int*)d_in[30];

    float* w = (float*)d_ws;            // float offsets, 16B aligned
    float* deg    = w;                  // 2048   [memset 16 KB covers deg+cnt]
    int*   cnt    = (int*)(w + 2048);   // 2048
    int*   rowptr = (int*)(w + 4096);   // 2049 (pad 2560)
    float* dinv   = w + 6656;           // 2048
    float* dself  = w + 8704;           // 2048
    int*   fill   = (int*)(w + 10752);  // 2048
    int*   csrc   = (int*)(w + 12800);  // 65536
    float* cnrm   = w + 78336;          // 65536
    float* Wzp    = w + 143872;         // 2048
    float* Whp    = w + 145920;         // 2048
    float* bUV    = w + 147968;         // 128
    float* ag     = w + 148096;         // 131072
    float* bjp    = w + 279168;         // 131072
    float* hw1    = w + 410240;         // 131072
    float* hw2    = w + 541312;         // 131072

    hipMemsetAsync(deg, 0, 16384, stream);
    k_deg_wcomb<<<258, 256, 0, stream>>>(ei, ew, Wcz, Wlz, bcz, blz, Wch, Wlh, bch, blh,
                                         deg, cnt, Wzp, Whp, bUV);
    k_scan<<<1, 1024, 0, stream>>>(deg, cnt, rowptr, dinv, dself, fill);
    k_csr<<<N_EDGES/256, 256, 0, stream>>>(ei, ew, dinv, rowptr, fill, csrc, cnrm);
    k_gate<<<N_NODES, 320, 0, stream>>>(x, dself, rowptr, csrc, cnrm, bUV, Wzp, Whp,
                                        Wred, bred, Wi1, bi1, Wc1, ag, bjp, hw1);
    k_gcn1<<<N_NODES, 256, 0, stream>>>(hw1, dself, rowptr, csrc, cnrm, bc1, g1, be1, Wc2, hw2);
    k_gcn2s<<<N_NODES + 4096, 256, 0, stream>>>(hw2, dself, rowptr, csrc, cnrm,
                                                bc2, g2, be2, Wout, bout,
                                                ag, bjp, Wi2, bi2,
                                                (float*)d_out, (float*)d_out + N_NODES*OUT_F);
}

// Round 8
// 217.043 us; speedup vs baseline: 3.7455x; 1.0213x over previous
//
#include <hip/hip_runtime.h>
#include <math.h>

#define N_NODES 2048
#define N_EDGES 65536
#define SEQL 5
#define IN_F 32
#define HID 64
#define OUT_F 16
#define LN_EPS 1e-5f

// ================= k_deg_wcomb: 258 blocks x 256 =================
__global__ __launch_bounds__(256) void k_deg_wcomb(
        const int* __restrict__ ei, const float* __restrict__ ew,
        const float* __restrict__ Wcz, const float* __restrict__ Wlz,
        const float* __restrict__ bcz, const float* __restrict__ blz,
        const float* __restrict__ Wch, const float* __restrict__ Wlh,
        const float* __restrict__ bch, const float* __restrict__ blh,
        float* __restrict__ deg, int* __restrict__ cnt,
        float* __restrict__ Wzp, float* __restrict__ Whp, float* __restrict__ bUV){
    int b = blockIdx.x, t = threadIdx.x;
    if (b < 256){
        int e = b * 256 + t;
        int d = ei[N_EDGES + e];
        atomicAdd(&deg[d], ew[e]);
        atomicAdd(&cnt[d], 1);
    } else {
        const float* Wc = (b == 256) ? Wcz : Wch;
        const float* Wl = (b == 256) ? Wlz : Wlh;
        const float* bc = (b == 256) ? bcz : bch;
        const float* bl = (b == 256) ? blz : blh;
        float* Wp = (b == 256) ? Wzp : Whp;
        for (int idx = t; idx < IN_F*HID; idx += 256){
            int i = idx >> 6, f = idx & 63;
            float s = 0.f;
            #pragma unroll 8
            for (int k = 0; k < HID; ++k) s += Wc[i*HID+k] * Wl[k*HID+f];
            Wp[idx] = s;
        }
        if (t < HID){
            float s = bl[t];
            for (int k = 0; k < HID; ++k) s += bc[k] * Wl[k*HID+t];
            bUV[(b-256)*HID + t] = s;
        }
    }
}

// ================= k_scan: 1 block x 1024 =================
__global__ __launch_bounds__(1024) void k_scan(
        const float* __restrict__ deg, const int* __restrict__ cnt,
        int* __restrict__ rowptr, float* __restrict__ dinv, float* __restrict__ dself,
        int* __restrict__ fill){
    __shared__ int sc[1024];
    int t = threadIdx.x;
    int c0 = cnt[2*t], c1 = cnt[2*t+1];
    int ts = c0 + c1;
    sc[t] = ts;
    __syncthreads();
    for (int off = 1; off < 1024; off <<= 1){
        int v = (t >= off) ? sc[t - off] : 0;
        __syncthreads();
        sc[t] += v;
        __syncthreads();
    }
    int exc = sc[t] - ts;
    rowptr[2*t]   = exc;
    rowptr[2*t+1] = exc + c0;
    if (t == 1023) rowptr[N_NODES] = sc[t];
    float i0 = 1.f / sqrtf(deg[2*t] + 1.f);
    float i1 = 1.f / sqrtf(deg[2*t+1] + 1.f);
    dinv[2*t] = i0;     dinv[2*t+1] = i1;
    dself[2*t] = i0*i0; dself[2*t+1] = i1*i1;
    fill[2*t] = 0;      fill[2*t+1] = 0;
}

// ================= CSR fill: interleaved (src, nrm) pairs =================
__global__ void k_csr(const int* __restrict__ ei, const float* __restrict__ ew,
                      const float* __restrict__ dinv, const int* __restrict__ rowptr,
                      int* __restrict__ fill, float2* __restrict__ cedge){
    int e = blockIdx.x * 256 + threadIdx.x;
    if (e < N_EDGES){
        int s = ei[e], d = ei[N_EDGES + e];
        int pos = rowptr[d] + atomicAdd(&fill[d], 1);
        float2 v;
        v.x = __int_as_float(s);
        v.y = dinv[s] * ew[e] * dinv[d];
        cedge[pos] = v;
    }
}

// ================= k_gate: 40 edge slots x 8 f4-lanes -> 1 gather round =================
__global__ __launch_bounds__(320) void k_gate(const float* __restrict__ x,
        const float* __restrict__ dself, const int* __restrict__ rowptr,
        const float2* __restrict__ cedge,
        const float* __restrict__ bUV, const float* __restrict__ Wzp, const float* __restrict__ Whp,
        const float* __restrict__ Wred, const float* __restrict__ bred,
        const float* __restrict__ Wi1, const float* __restrict__ bi1, const float* __restrict__ Wc1,
        float* __restrict__ ag, float* __restrict__ bjp, float* __restrict__ hw1){
    int n = blockIdx.x;
    int tid = threadIdx.x;
    __shared__ float part[40*SEQL*IN_F];       // 25.6 KB
    __shared__ float axs[SEQL][IN_F];
    __shared__ float hs[SEQL][HID];
    __shared__ float pw[SEQL][HID];
    __shared__ float hemb[HID];
    const int slot = tid >> 3, fl = tid & 7;   // 40 slots x 8 lanes (float4 each)
    const int f = tid & 63, t = tid >> 6;      // 5 waves for the dense phases
    int beg = rowptr[n], end = rowptr[n+1];
    const float4* X4 = (const float4*)x;
    float4 a0 = {0,0,0,0}, a1 = {0,0,0,0}, a2 = {0,0,0,0}, a3 = {0,0,0,0}, a4 = {0,0,0,0};
    for (int p = beg + slot; p < end; p += 40){
        float2 ed = cedge[p];
        int s = __float_as_int(ed.x); float c = ed.y;
        float4 x0 = X4[(0*N_NODES + s)*8 + fl];
        float4 x1 = X4[(1*N_NODES + s)*8 + fl];
        float4 x2 = X4[(2*N_NODES + s)*8 + fl];
        float4 x3 = X4[(3*N_NODES + s)*8 + fl];
        float4 x4v= X4[(4*N_NODES + s)*8 + fl];
        a0.x += c*x0.x; a0.y += c*x0.y; a0.z += c*x0.z; a0.w += c*x0.w;
        a1.x += c*x1.x; a1.y += c*x1.y; a1.z += c*x1.z; a1.w += c*x1.w;
        a2.x += c*x2.x; a2.y += c*x2.y; a2.z += c*x2.z; a2.w += c*x2.w;
        a3.x += c*x3.x; a3.y += c*x3.y; a3.z += c*x3.z; a3.w += c*x3.w;
        a4.x += c*x4v.x; a4.y += c*x4v.y; a4.z += c*x4v.z; a4.w += c*x4v.w;
    }
    *(float4*)&part[(slot*SEQL + 0)*IN_F + fl*4] = a0;
    *(float4*)&part[(slot*SEQL + 1)*IN_F + fl*4] = a1;
    *(float4*)&part[(slot*SEQL + 2)*IN_F + fl*4] = a2;
    *(float4*)&part[(slot*SEQL + 3)*IN_F + fl*4] = a3;
    *(float4*)&part[(slot*SEQL + 4)*IN_F + fl*4] = a4;
    __syncthreads();
    if (tid < SEQL*IN_F){
        int tt = tid >> 5, ff = tid & 31;
        float s = dself[n] * x[(tt*N_NODES + n)*IN_F + ff];
        #pragma unroll 8
        for (int sl = 0; sl < 40; ++sl) s += part[(sl*SEQL + tt)*IN_F + ff];
        axs[tt][ff] = s;
    }
    __syncthreads();
    {   // 5 waves: gate for timestep t
        float zz = bUV[f], hh = bUV[HID + f];
        #pragma unroll
        for (int i = 0; i < IN_F; ++i){
            float a = axs[t][i];               // wave-uniform LDS broadcast
            zz += a * Wzp[i*HID + f];
            hh += a * Whp[i*HID + f];
        }
        float z = 1.f / (1.f + expf(-zz));
        hs[t][f] = (1.f - z) * tanhf(hh);
    }
    __syncthreads();
    {   float pp = 0.f;
        #pragma unroll
        for (int k = 0; k < HID; ++k) pp += hs[t][k] * Wred[(t*HID + k)*HID + f];
        pw[t][f] = pp;
    }
    __syncthreads();
    if (tid < HID){
        float hr = bred[tid];
        #pragma unroll
        for (int t2 = 0; t2 < SEQL; ++t2) hr += pw[t2][tid];
        hemb[tid] = hr;
    }
    __syncthreads();
    if (t < 3){
        const float* W = (t == 0) ? Wi1 : (t == 1) ? (Wi1 + HID*HID) : Wc1;
        float acc = (t == 1) ? bi1[f] : 0.f;
        #pragma unroll
        for (int k = 0; k < HID; ++k) acc += hemb[k] * W[k*HID + f];
        float* O = (t == 0) ? ag : (t == 1) ? bjp : hw1;
        O[n*HID + f] = acc;                    // bjp has bi1 folded in
    }
}

// ================= gcn1: 32 slots x 16 f4-lanes, LN+relu, premultiply Wc2 =================
__global__ __launch_bounds__(512) void k_gcn1(
        const float* __restrict__ hw1, const float* __restrict__ dself,
        const int* __restrict__ rowptr, const float2* __restrict__ cedge,
        const float* __restrict__ bc1, const float* __restrict__ g1, const float* __restrict__ be1,
        const float* __restrict__ Wc2, float* __restrict__ hw2){
    int n = blockIdx.x;
    int tid = threadIdx.x;
    __shared__ float part[32*HID];             // 8 KB
    __shared__ float hsh[HID];
    __shared__ float red8[8*HID];
    const int slot = tid >> 4, fl = tid & 15;
    const int f = tid & 63, w = tid >> 6;
    int beg = rowptr[n], end = rowptr[n+1];
    const float4* H4 = (const float4*)hw1;
    float4 acc = {0,0,0,0};
    for (int p = beg + slot; p < end; p += 32){
        float2 ed = cedge[p];
        int s = __float_as_int(ed.x); float c = ed.y;
        float4 h = H4[s*16 + fl];
        acc.x += c*h.x; acc.y += c*h.y; acc.z += c*h.z; acc.w += c*h.w;
    }
    *(float4*)&part[slot*HID + fl*4] = acc;
    __syncthreads();
    if (w == 0){
        float g = bc1[f] + dself[n] * hw1[n*HID + f];
        #pragma unroll 8
        for (int sl = 0; sl < 32; ++sl) g += part[sl*HID + f];
        float sum = g;
        for (int o = 32; o > 0; o >>= 1) sum += __shfl_xor(sum, o, 64);
        float mu = sum * (1.f/64.f);
        float d = g - mu;
        float vs = d * d;
        for (int o = 32; o > 0; o >>= 1) vs += __shfl_xor(vs, o, 64);
        float var = vs * (1.f/64.f);
        float h = d * (1.f / sqrtf(var + LN_EPS)) * g1[f] + be1[f];
        hsh[f] = fmaxf(h, 0.f);
    }
    __syncthreads();
    float s = 0.f;
    #pragma unroll
    for (int k = 0; k < 8; ++k) s += hsh[w*8 + k] * Wc2[(w*8 + k)*HID + f];
    red8[w*HID + f] = s;
    __syncthreads();
    if (w == 0){
        float o = 0.f;
        #pragma unroll
        for (int k = 0; k < 8; ++k) o += red8[k*HID + f];
        hw2[n*HID + f] = o;
    }
}

// ================= gcn2 (blocks 0..2047) + scores 32x64 tiles (2048..4095) =================
__global__ __launch_bounds__(512) void k_gcn2s(
        const float* __restrict__ hw2, const float* __restrict__ dself,
        const int* __restrict__ rowptr, const float2* __restrict__ cedge,
        const float* __restrict__ bc2, const float* __restrict__ g2, const float* __restrict__ be2,
        const float* __restrict__ Wout, const float* __restrict__ bout,
        const float* __restrict__ ag, const float* __restrict__ bjp,
        const float* __restrict__ Wi2, const float* __restrict__ bi2,
        float* __restrict__ outp, float* __restrict__ outs){
    int blk = blockIdx.x;
    int tid = threadIdx.x;
    if (blk < N_NODES){
        __shared__ float part[32*HID];
        __shared__ float hsh[HID];
        int n = blk;
        const int slot = tid >> 4, fl = tid & 15;
        const int f = tid & 63, w = tid >> 6;
        int beg = rowptr[n], end = rowptr[n+1];
        const float4* H4 = (const float4*)hw2;
        float4 acc = {0,0,0,0};
        for (int p = beg + slot; p < end; p += 32){
            float2 ed = cedge[p];
            int s = __float_as_int(ed.x); float c = ed.y;
            float4 h = H4[s*16 + fl];
            acc.x += c*h.x; acc.y += c*h.y; acc.z += c*h.z; acc.w += c*h.w;
        }
        *(float4*)&part[slot*HID + fl*4] = acc;
        __syncthreads();
        if (w == 0){
            float g = bc2[f] + dself[n] * hw2[n*HID + f];
            #pragma unroll 8
            for (int sl = 0; sl < 32; ++sl) g += part[sl*HID + f];
            float sum = g;
            for (int o = 32; o > 0; o >>= 1) sum += __shfl_xor(sum, o, 64);
            float mu = sum * (1.f/64.f);
            float d = g - mu;
            float vs = d * d;
            for (int o = 32; o > 0; o >>= 1) vs += __shfl_xor(vs, o, 64);
            float var = vs * (1.f/64.f);
            float h = d * (1.f / sqrtf(var + LN_EPS)) * g2[f] + be2[f];
            hsh[f] = fmaxf(h, 0.f);
        }
        __syncthreads();
        if (w == 0 && f < OUT_F){
            float s = bout[f];
            #pragma unroll
            for (int k = 0; k < HID; ++k) s += hsh[k] * Wout[k*OUT_F + f];
            outp[n*OUT_F + f] = s;
        }
    } else {
        __shared__ float bs[64*65];
        __shared__ float wv[64];
        int tl = blk - N_NODES;
        int j0 = (tl & 31) * 64;
        int i0 = (tl >> 5) * 32;
        for (int idx = tid; idx < 4096; idx += 512){
            int jj = idx >> 6, f = idx & 63;
            bs[jj*65 + f] = bjp[(j0 + jj)*HID + f];
        }
        if (tid < 64) wv[tid] = Wi2[tid];
        __syncthreads();
        int tj = tid & 63;
        int w = __builtin_amdgcn_readfirstlane(tid >> 6);   // wave-uniform -> scalar a-loads
        const float* ar = ag + (i0 + w*4)*HID;
        float bi2v = bi2[0];
        float acc0 = 0.f, acc1 = 0.f, acc2 = 0.f, acc3 = 0.f;
        #pragma unroll
        for (int f = 0; f < 64; ++f){
            float bv = bs[tj*65 + f];
            float wf = wv[f];
            acc0 += fmaxf(ar[       f] + bv, 0.f) * wf;
            acc1 += fmaxf(ar[ 64 +  f] + bv, 0.f) * wf;
            acc2 += fmaxf(ar[128 +  f] + bv, 0.f) * wf;
            acc3 += fmaxf(ar[192 +  f] + bv, 0.f) * wf;
        }
        long ro = (long)(i0 + w*4) * N_NODES + j0 + tj;
        outs[ro                ] = acc0 + bi2v;
        outs[ro +     N_NODES  ] = acc1 + bi2v;
        outs[ro + 2L* N_NODES  ] = acc2 + bi2v;
        outs[ro + 3L* N_NODES  ] = acc3 + bi2v;
    }
}

extern "C" void kernel_launch(void* const* d_in, const int* in_sizes, int n_in,
                              void* d_out, int out_size, void* d_ws, size_t ws_size,
                              hipStream_t stream){
    const float* x   = (const float*)d_in[0];
    const float* ew  = (const float*)d_in[1];
    const float* Wcz = (const float*)d_in[2];  const float* bcz = (const float*)d_in[3];
    const float* Wlz = (const float*)d_in[4];  const float* blz = (const float*)d_in[5];
    // d_in[6..9]: Wcr/bcr/Wlr/blr — dead code (H=0 so reset gate has no effect)
    const float* Wch = (const float*)d_in[10]; const float* bch = (const float*)d_in[11];
    const float* Wlh = (const float*)d_in[12]; const float* blh = (const float*)d_in[13];
    const float* Wred= (const float*)d_in[14]; const float* bred= (const float*)d_in[15];
    const float* Wc1 = (const float*)d_in[16]; const float* bc1 = (const float*)d_in[17];
    const float* Wc2 = (const float*)d_in[18]; const float* bc2 = (const float*)d_in[19];
    const float* g1  = (const float*)d_in[20]; const float* be1 = (const float*)d_in[21];
    const float* g2  = (const float*)d_in[22]; const float* be2 = (const float*)d_in[23];
    const float* Wout= (const float*)d_in[24]; const float* bout= (const float*)d_in[25];
    const float* Wi1 = (const float*)d_in[26]; const float* bi1 = (const float*)d_in[27];
    const float* Wi2 = (const float*)d_in[28]; const float* bi2 = (const float*)d_in[29];
    const int*  ei  = (const int*)d_in[30];

    float* w = (float*)d_ws;            // float offsets, 16B aligned
    float* deg    = w;                  // 2048   [memset 16 KB covers deg+cnt]
    int*   cnt    = (int*)(w + 2048);   // 2048
    int*   rowptr = (int*)(w + 4096);   // 2049 (pad 2560)
    float* dinv   = w + 6656;           // 2048
    float* dself  = w + 8704;           // 2048
    int*   fill   = (int*)(w + 10752);  // 2048
    float2* cedge = (float2*)(w + 12800); // 65536 pairs = 131072 floats
    float* Wzp    = w + 143872;         // 2048
    float* Whp    = w + 145920;         // 2048
    float* bUV    = w + 147968;         // 128
    float* ag     = w + 148096;         // 131072
    float* bjp    = w + 279168;         // 131072
    float* hw1    = w + 410240;         // 131072
    float* hw2    = w + 541312;         // 131072

    hipMemsetAsync(deg, 0, 16384, stream);
    k_deg_wcomb<<<258, 256, 0, stream>>>(ei, ew, Wcz, Wlz, bcz, blz, Wch, Wlh, bch, blh,
                                         deg, cnt, Wzp, Whp, bUV);
    k_scan<<<1, 1024, 0, stream>>>(deg, cnt, rowptr, dinv, dself, fill);
    k_csr<<<N_EDGES/256, 256, 0, stream>>>(ei, ew, dinv, rowptr, fill, cedge);
    k_gate<<<N_NODES, 320, 0, stream>>>(x, dself, rowptr, cedge, bUV, Wzp, Whp,
                                        Wred, bred, Wi1, bi1, Wc1, ag, bjp, hw1);
    k_gcn1<<<N_NODES, 512, 0, stream>>>(hw1, dself, rowptr, cedge, bc1, g1, be1, Wc2, hw2);
    k_gcn2s<<<N_NODES + 2048, 512, 0, stream>>>(hw2, dself, rowptr, cedge,
                                                bc2, g2, be2, Wout, bout,
                                                ag, bjp, Wi2, bi2,
                                                (float*)d_out, (float*)d_out + N_NODES*OUT_F);
}